// Round 14
// baseline (8012.119 us; speedup 1.0000x reference)
//
#include <hip/hip_runtime.h>
#include <hip/hip_bf16.h>

typedef __attribute__((ext_vector_type(4))) float f32x4;
typedef __attribute__((ext_vector_type(8))) short s16x8;

#define DEVFN static __device__ __forceinline__

// ---- problem sizes ----
#define TT  160
#define BB  640
#define DD  40
#define HH  768
#define PP  256
#define G4H 3072

// ---- geometry ----
// 144 gate blocks: 3 layers x 48 col-slices (16 h-cols = 64 z-cols), ALL 640 rows.
//   Wph = Wp @ Wh fused into LDS: the gate<->gate recurrence needs ONE handoff/step.
// 48 proj blocks: off the recurrent cycle entirely (feed next layer + epilogue).
#define NWG   192
#define NTHR  512      // 8 waves = 2 waves/SIMD (R13-proven)

#define KH  256
#define KX0 64         // layer0 x-K padded 40 -> 64
#define KS  768        // fused recurrent K: s(t-1) @ Wph

// LDS strides (elements); +8 pad keeps 16B alignment, breaks worst conflicts
#define STW1 840       // layer0: 64+768+8
#define STW2 1032      // layer1/2: 256+768+8
#define STP  776       // proj: 768+8
#define LDS_ELEMS 66048  // 64*1032 = 132,096 bytes

// ---- workspace layout ----
// Sb and Hr are DEPTH-4 rings: one acquire-fence per 4 steps (R12-proven).
#define XP_BYTES   (TT*BB*64*2)
#define HR_BYTES   (3*4*BB*PP*2)
#define SB_BYTES   (3*4*BB*HH*2)
#define XP_OFF     0
#define HR_OFF     (XP_OFF + XP_BYTES)
#define SB_OFF     (HR_OFF + HR_BYTES)
#define SYNC_OFF   (SB_OFF + SB_BYTES)
#define SYNC_BYTES 4096

DEVFN float sigm(float v)  { return __fdividef(1.f, 1.f + __expf(-v)); }
DEVFN float tanh_(float v) { return 2.f * __fdividef(1.f, 1.f + __expf(-2.f * v)) - 1.f; }
DEVFN f32x4 f4zero() { f32x4 v; v[0]=0.f; v[1]=0.f; v[2]=0.f; v[3]=0.f; return v; }

// write-through bf16 store: at coherence point once vmcnt retires (R8-proven).
DEVFN void gst_b16(__hip_bfloat16* p, __hip_bfloat16 v) {
  unsigned short u = __builtin_bit_cast(unsigned short, v);
  asm volatile("global_store_short %0, %1, off sc0 sc1" :: "v"(p), "v"(u));
}

// cache-bypassing 4B load/store (coherence-point access, fresh values)
DEVFN unsigned ld_cc(const unsigned* p) {
  unsigned v;
  asm volatile("global_load_dword %0, %1, off sc0 sc1\n\ts_waitcnt vmcnt(0)"
               : "=v"(v) : "v"(p) : "memory");
  return v;
}
DEVFN void st_cc(unsigned* p, unsigned v) {
  asm volatile("global_store_dword %0, %1, off sc0 sc1" :: "v"(p), "v"(v) : "memory");
}
DEVFN void ld2_cc(const unsigned* p0, const unsigned* p1, unsigned& a, unsigned& b) {
  asm volatile("global_load_dword %0, %2, off sc0 sc1\n\t"
               "global_load_dword %1, %3, off sc0 sc1\n\t"
               "s_waitcnt vmcnt(0)"
               : "=&v"(a), "=&v"(b) : "v"(p0), "v"(p1) : "memory");
}
DEVFN void ld3_cc(const unsigned* p0, const unsigned* p1, const unsigned* p2,
                  unsigned& a, unsigned& b, unsigned& c) {
  asm volatile("global_load_dword %0, %3, off sc0 sc1\n\t"
               "global_load_dword %1, %4, off sc0 sc1\n\t"
               "global_load_dword %2, %5, off sc0 sc1\n\t"
               "s_waitcnt vmcnt(0)"
               : "=&v"(a), "=&v"(b), "=&v"(c)
               : "v"(p0), "v"(p1), "v"(p2) : "memory");
}

DEVFN void fence_acq() { __builtin_amdgcn_fence(__ATOMIC_ACQUIRE, "agent"); }

// ---- sync word layout (unsigned, within 4096B):
//   [0..191]    init-barrier flags (one per block)
//   SFLAG(l,j) = 256 + (l*48+j)*4   gate col-slice "s(t) done" counters (value t+1)
//   PFLAG(l,p) = 832 + (l*16+p)*4   proj "h(t) done" counters (value t+1)
#define SFLAG(s,l,j) ((s) + 256 + ((l)*48+(j))*4)
#define PFLAG(s,l,p) ((s) + 832 + ((l)*16+(p))*4)

// one-time full-grid barrier (packs done); decentralized: every block polls all 192.
DEVFN void init_barrier(unsigned* sync, int bid, int tid) {
  __syncthreads();                 // drains vmcnt: Xp pack stores at coherence point
  if (tid == 0) st_cc(sync + bid, 1u);
  if (tid < 64) {
    unsigned a, b, c;
    for (;;) {
      ld3_cc(sync + tid, sync + 64 + tid, sync + 128 + tid, a, b, c);
      if (__all((a >= 1u) & (b >= 1u) & (c >= 1u))) break;
    }
    fence_acq();
  }
  __syncthreads();
}

// generic wait (epilogue etc.): nf flags (16B stride) all >= thr.
DEVFN void wait_flags(const unsigned* base, int nf, int thr, int tid, bool dofence) {
  if (thr <= 0) return;
  if (tid < 64) {
    const unsigned* p = base + tid * 4;
    for (;;) {
      int v = (tid < nf) ? (int)ld_cc(p) : 0x7fffffff;
      if (__all(v >= thr)) break;
    }
    if (dofence) fence_acq();
  }
  __syncthreads();
}

// gate combined wait: 48 own-layer sflags >= t (s(t-1) ready), 16 own pflags >=
// t-3 (Sb ring back-pressure, rarely binds), and (l>0) 16 prev-layer pflags >=
// t+1 (h_{l-1}(t) ready for the x-part). Lanes 0-47: sflags; 48-63: pflag pair.
DEVFN void gate_wait(const unsigned* sf, const unsigned* pfo, const unsigned* pfp,
                     int hasprv, int t, int tid, bool dofence) {
  if (tid < 64) {
    const unsigned* p1 = (tid < 48) ? (sf + tid * 4) : (pfo + (tid - 48) * 4);
    const int thr1     = (tid < 48) ? t : (t - 3);
    const unsigned* p2 = (hasprv && tid >= 48) ? (pfp + (tid - 48) * 4) : p1;
    const int thr2     = (hasprv && tid >= 48) ? (t + 1) : thr1;
    for (;;) {
      unsigned a, b;
      ld2_cc(p1, p2, a, b);
      if (__all(((int)a >= thr1) & ((int)b >= thr2))) break;
    }
    if (dofence) fence_acq();
  }
  __syncthreads();
}

// proj wait: 48 own-layer sflags >= t+1, plus (l<2) 48 next-layer sflags >= t-3
// (Hr ring back-pressure: gates(l+1) consumed h_l(t-4)).
DEVFN void proj_wait(const unsigned* s1, const unsigned* s2, int has2,
                     int thr1, int thr2, int tid, bool dofence) {
  if (tid < 64) {
    const unsigned* p1 = (tid < 48) ? (s1 + tid * 4) : s1;
    const unsigned* p2 = (has2 && tid < 48) ? (s2 + tid * 4) : p1;
    for (;;) {
      unsigned a, b;
      ld2_cc(p1, p2, a, b);
      int v1 = (tid < 48) ? (int)a : 0x7fffffff;
      int v2 = (has2 && tid < 48 && thr2 > 0) ? (int)b : 0x7fffffff;
      if (__all((v1 >= thr1) & (v2 >= thr2))) break;
    }
    if (dofence) fence_acq();
  }
  __syncthreads();
}

// announce: data stores drained (syncthreads => vmcnt(0)), then flag store.
DEVFN void set_flag(unsigned* p, unsigned v, int tid) {
  __syncthreads();
  if (tid == 0) st_cc(p, v);
}

__global__ __launch_bounds__(NTHR, 1)
void lstmp_persistent(const float* __restrict__ xin,
                      const float* __restrict__ W0, const float* __restrict__ b0, const float* __restrict__ Wp0,
                      const float* __restrict__ W1, const float* __restrict__ b1, const float* __restrict__ Wp1,
                      const float* __restrict__ W2, const float* __restrict__ b2, const float* __restrict__ Wp2,
                      float* __restrict__ outp, unsigned char* __restrict__ ws)
{
  __shared__ __align__(16) __hip_bfloat16 lds[LDS_ELEMS];

  const int bid  = blockIdx.x;
  const int tid  = threadIdx.x;
  const int lane = tid & 63;
  const int wave = tid >> 6;      // 0..7
  const int q    = lane >> 4;     // 0..3
  const int c16  = lane & 15;

  __hip_bfloat16* Xp = (__hip_bfloat16*)(ws + XP_OFF);  // [160][640][64] bf16, cols>=40 zero
  __hip_bfloat16* Hr = (__hip_bfloat16*)(ws + HR_OFF);  // [3][4 ring][640][256]; slot (t+1)&3 holds h(t)
  __hip_bfloat16* Sb = (__hip_bfloat16*)(ws + SB_OFF);  // [3][4 ring][640][768]; slot t&3 holds s(t)
  unsigned* sync     = (unsigned*)(ws + SYNC_OFF);

  // ---- XCD-aware role decode (performance heuristic only; correctness is
  // placement-independent). xcd<6: gates (l = xcd>>1, 48 col-slices over 2
  // XCDs -> each XCD's 24 blocks share the layer s-tile in its L2).
  // xcd 6,7: proj (l = slot>>3; 8 per layer per XCD).
  const int xcd  = bid & 7;
  const int slot = bid >> 3;      // 0..23
  const bool isGate = (xcd < 6);
  int l = 0, hg = 0, mt = 0, nt = 0;
  if (isGate) { l = xcd >> 1; hg = (xcd & 1) * 24 + slot; }          // 0..47
  else        { l = slot >> 3; int r = slot & 7; mt = (xcd - 6) * 2 + (r >> 2); nt = r & 3; }

  const int KX  = (l == 0) ? KX0 : 256;
  const int STW = (l == 0) ? STW1 : STW2;

  const float* Wl  = (l == 0) ? W0  : ((l == 1) ? W1  : W2);
  const float* bl  = (l == 0) ? b0  : ((l == 1) ? b1  : b2);
  const float* Wpl = (l == 0) ? Wp0 : ((l == 1) ? Wp1 : Wp2);

  // ---------- pre-phase: pack x -> Xp (all blocks share the work) ----------
  for (int e = bid * NTHR + tid; e < TT * BB * 64; e += NWG * NTHR) {
    int k  = e & 63;
    int tb = e >> 6;
    float v = (k < DD) ? xin[(size_t)tb * DD + k] : 0.f;
    gst_b16(&Xp[e], __float2bfloat16(v));
  }

  // ---------- pre-phase: pack weights into this block's LDS ----------
  if (isGate) {
    // Wt[nn][kk]: nn = g*16 + hc (64 z-cols), kk<KX: x-part; kk>=KX: Wph.
    for (int idx = tid; idx < 64 * KX; idx += NTHR) {
      int kk = idx >> 6;
      int nn = idx & 63;
      int col = (nn >> 4) * HH + hg * 16 + (nn & 15);
      float v = (l == 0) ? ((kk < DD) ? Wl[(size_t)kk * G4H + col] : 0.f)
                         : Wl[(size_t)kk * G4H + col];
      lds[nn * STW + kk] = __float2bfloat16(v);
    }
    // Wph[hrow][nn] = sum_k Wp[hrow][k] * W[din+k][col]  (one-time fp32 GEMV;
    // Wp read is wave-uniform, Wl read lane-coalesced). R2-verified numerics.
    const int din = (l == 0) ? DD : 256;
    for (int idx = tid; idx < 64 * KS; idx += NTHR) {
      int nn   = idx & 63;
      int hrow = idx >> 6;
      int col  = (nn >> 4) * HH + hg * 16 + (nn & 15);
      float a0 = 0.f;
#pragma unroll 4
      for (int k = 0; k < PP; ++k)
        a0 += Wpl[(size_t)hrow * PP + k] * Wl[(size_t)(din + k) * G4H + col];
      lds[nn * STW + KX + hrow] = __float2bfloat16(a0);
    }
  } else {
    for (int idx = tid; idx < 64 * HH; idx += NTHR) {
      int kk = idx >> 6;
      int nn = idx & 63;
      lds[nn * STP + kk] = __float2bfloat16(Wpl[(size_t)kk * PP + nt * 64 + nn]);
    }
  }

  init_barrier(sync, bid, tid);     // packs done (Xp + LDS weights + Wph)

  if (isGate) {
    // ----- GATE PATH: 8 waves x 80 rows, block owns 64 z-cols (16 h-cols) -----
    unsigned* myflag = SFLAG(sync, l, hg);
    const unsigned* sf_own = SFLAG(sync, l, 0);
    const unsigned* pf_own = PFLAG(sync, l, 0);
    const unsigned* pf_prv = (l > 0) ? PFLAG(sync, l - 1, 0) : PFLAG(sync, l, 0);

    const int m0g = wave * 80;
    float biasv[4];
#pragma unroll
    for (int g = 0; g < 4; ++g) biasv[g] = bl[g * HH + hg * 16 + c16];

    f32x4 acc[5][4];
    float cst[5][4];
#pragma unroll
    for (int mi = 0; mi < 5; ++mi)
#pragma unroll
      for (int g = 0; g < 4; ++g) { acc[mi][g] = f4zero(); cst[mi][g] = 0.f; }

    // 2-deep k-ping-pong (R13-proven). A's K-offset is ks only; kbase applies
    // to the LDS B-tile rows exclusively. klen must be a multiple of 64.
    auto gate_gemm = [&](const __hip_bfloat16* A, int lda, int kbase, int klen) {
      s16x8 a0[5], a1[5];
#pragma unroll
      for (int mi = 0; mi < 5; ++mi)
        a0[mi] = *(const s16x8*)(A + (size_t)(m0g + mi * 16 + c16) * lda + 8 * q);
#pragma unroll 1
      for (int it2 = 0; it2 < klen / 64; ++it2) {
        const int ks0 = it2 * 64, ks1 = ks0 + 32;
#pragma unroll
        for (int mi = 0; mi < 5; ++mi)
          a1[mi] = *(const s16x8*)(A + (size_t)(m0g + mi * 16 + c16) * lda + ks1 + 8 * q);
        s16x8 bv[4];
#pragma unroll
        for (int g = 0; g < 4; ++g)
          bv[g] = *(const s16x8*)(lds + (g * 16 + c16) * STW + kbase + ks0 + 8 * q);
#pragma unroll
        for (int mi = 0; mi < 5; ++mi)
#pragma unroll
          for (int g = 0; g < 4; ++g)
            acc[mi][g] = __builtin_amdgcn_mfma_f32_16x16x32_bf16(a0[mi], bv[g], acc[mi][g], 0, 0, 0);
        if (it2 + 1 < klen / 64) {
#pragma unroll
          for (int mi = 0; mi < 5; ++mi)
            a0[mi] = *(const s16x8*)(A + (size_t)(m0g + mi * 16 + c16) * lda + ks0 + 64 + 8 * q);
        }
#pragma unroll
        for (int g = 0; g < 4; ++g)
          bv[g] = *(const s16x8*)(lds + (g * 16 + c16) * STW + kbase + ks1 + 8 * q);
#pragma unroll
        for (int mi = 0; mi < 5; ++mi)
#pragma unroll
          for (int g = 0; g < 4; ++g)
            acc[mi][g] = __builtin_amdgcn_mfma_f32_16x16x32_bf16(a1[mi], bv[g], acc[mi][g], 0, 0, 0);
      }
    };

    auto gate_update = [&](int t) {
      __hip_bfloat16* S = Sb + ((size_t)l * 4 + ((unsigned)t & 3)) * BB * HH;
#pragma unroll
      for (int mi = 0; mi < 5; ++mi) {
#pragma unroll
        for (int r = 0; r < 4; ++r) {
          float iv = acc[mi][0][r] + biasv[0];
          float jv = acc[mi][1][r] + biasv[1];
          float fv = acc[mi][2][r] + biasv[2];
          float ov = acc[mi][3][r] + biasv[3];
          float c  = sigm(fv + 1.f) * cst[mi][r] + sigm(iv) * tanh_(jv);
          cst[mi][r] = c;
          float sv = sigm(ov) * tanh_(c);
          gst_b16(&S[(size_t)(m0g + mi * 16 + q * 4 + r) * HH + hg * 16 + c16],
                  __float2bfloat16(sv));
        }
#pragma unroll
        for (int g = 0; g < 4; ++g) acc[mi][g] = f4zero();
      }
    };

    for (int t = 0; t < TT; ++t) {
      // ONE handoff per step: s(t-1) from all 48 col-slices + x-input + ring guards.
      gate_wait(sf_own, pf_own, pf_prv, l > 0, t, tid, (t & 3) == 0);
      // x-part: z_x(t)
      if (l == 0) gate_gemm(Xp + (size_t)t * BB * 64, 64, 0, KX0);
      else        gate_gemm(Hr + ((size_t)(l - 1) * 4 + ((unsigned)(t + 1) & 3)) * BB * PP, PP, 0, 256);
      // recurrent part: z_h(t) = s(t-1) @ Wph  (s(-1)=0 -> skip at t=0)
      if (t > 0) gate_gemm(Sb + ((size_t)l * 4 + ((unsigned)(t - 1) & 3)) * BB * HH, HH, KX, KS);
      gate_update(t);
      set_flag(myflag, (unsigned)(t + 1), tid);
    }
  } else {
    // ----- PROJ PATH (off the recurrent cycle): waves 0-3 work, 4-deep ring -----
    unsigned* myflag = PFLAG(sync, l, mt * 4 + nt);
    const unsigned* sf_own = SFLAG(sync, l, 0);
    const unsigned* sf_nxt = (l < 2) ? SFLAG(sync, l + 1, 0) : SFLAG(sync, l, 0);
    const int m0p = mt * 160 + ((wave & 3) >> 1) * 80;
    const int np0 = (wave & 1) * 32;

    for (int t = 0; t < TT; ++t) {
      proj_wait(sf_own, sf_nxt, l < 2 ? 1 : 0, t + 1, t - 3, tid, (t & 3) == 0);

      if (wave < 4) {
        const __hip_bfloat16* A = Sb + ((size_t)l * 4 + ((unsigned)t & 3)) * BB * HH;
        const __hip_bfloat16* ab[5];
#pragma unroll
        for (int mi = 0; mi < 5; ++mi)
          ab[mi] = A + (size_t)(m0p + mi * 16 + c16) * HH + 8 * q;

        f32x4 pa[5][2];
#pragma unroll
        for (int mi = 0; mi < 5; ++mi) { pa[mi][0] = f4zero(); pa[mi][1] = f4zero(); }

        s16x8 r0[5], r1[5], r2[5], r3[5];   // 4-deep static prefetch ring
#pragma unroll
        for (int mi = 0; mi < 5; ++mi) {
          r0[mi] = *(const s16x8*)(ab[mi] + 0);
          r1[mi] = *(const s16x8*)(ab[mi] + 32);
          r2[mi] = *(const s16x8*)(ab[mi] + 64);
          r3[mi] = *(const s16x8*)(ab[mi] + 96);
        }

#define PSLICE(RB, S)                                                          \
        {                                                                      \
          s16x8 bv0 = *(const s16x8*)(lds + (np0 + c16) * STP + (S) * 32 + 8 * q);      \
          s16x8 bv1 = *(const s16x8*)(lds + (np0 + 16 + c16) * STP + (S) * 32 + 8 * q); \
          _Pragma("unroll")                                                    \
          for (int mi = 0; mi < 5; ++mi) {                                     \
            pa[mi][0] = __builtin_amdgcn_mfma_f32_16x16x32_bf16(RB[mi], bv0, pa[mi][0], 0, 0, 0); \
            pa[mi][1] = __builtin_amdgcn_mfma_f32_16x16x32_bf16(RB[mi], bv1, pa[mi][1], 0, 0, 0); \
          }                                                                    \
          if ((S) + 4 < 24) {                                                  \
            _Pragma("unroll")                                                  \
            for (int mi = 0; mi < 5; ++mi)                                     \
              RB[mi] = *(const s16x8*)(ab[mi] + ((S) + 4) * 32);               \
          }                                                                    \
        }

        PSLICE(r0, 0)  PSLICE(r1, 1)  PSLICE(r2, 2)  PSLICE(r3, 3)
        PSLICE(r0, 4)  PSLICE(r1, 5)  PSLICE(r2, 6)  PSLICE(r3, 7)
        PSLICE(r0, 8)  PSLICE(r1, 9)  PSLICE(r2, 10) PSLICE(r3, 11)
        PSLICE(r0, 12) PSLICE(r1, 13) PSLICE(r2, 14) PSLICE(r3, 15)
        PSLICE(r0, 16) PSLICE(r1, 17) PSLICE(r2, 18) PSLICE(r3, 19)
        PSLICE(r0, 20) PSLICE(r1, 21) PSLICE(r2, 22) PSLICE(r3, 23)
#undef PSLICE

        __hip_bfloat16* Hd = Hr + ((size_t)l * 4 + ((unsigned)(t + 1) & 3)) * BB * PP;
#pragma unroll
        for (int mi = 0; mi < 5; ++mi)
#pragma unroll
          for (int ni = 0; ni < 2; ++ni)
#pragma unroll
            for (int r = 0; r < 4; ++r)
              gst_b16(&Hd[(size_t)(m0p + mi * 16 + q * 4 + r) * PP + nt * 64 + np0 + ni * 16 + c16],
                      __float2bfloat16(pa[mi][ni][r]));
      }

      set_flag(myflag, (unsigned)(t + 1), tid);
    }
  }

  // ---------- epilogue: L2-normalize h_2(159) (ring slot (159+1)&3 = 0) ----------
  wait_flags(PFLAG(sync, 2, 0), 16, TT, tid, true);
  const __hip_bfloat16* hf = Hr + (size_t)(2 * 4 + 0) * BB * PP;
  float* red = reinterpret_cast<float*>(lds);   // weights dead now, reuse LDS
  const int half = tid >> 8;                    // 0,1: two rows per iteration
  const int col  = tid & 255;
  for (int row0 = bid * 2; row0 < BB; row0 += NWG * 2) {
    const int row = row0 + half;
    float v = __bfloat162float(hf[(size_t)row * PP + col]);
    float ssq = v * v;
#pragma unroll
    for (int off = 32; off > 0; off >>= 1) ssq += __shfl_down(ssq, off, 64);
    if (lane == 0) red[wave] = ssq;
    __syncthreads();
    float tot = red[half * 4 + 0] + red[half * 4 + 1] + red[half * 4 + 2] + red[half * 4 + 3];
    outp[(size_t)row * PP + col] = v * __fdividef(1.f, sqrtf(tot) + 1e-6f);
    __syncthreads();
  }
}

extern "C" void kernel_launch(void* const* d_in, const int* in_sizes, int n_in,
                              void* d_out, int out_size, void* d_ws, size_t ws_size,
                              hipStream_t stream) {
  (void)in_sizes; (void)n_in; (void)out_size; (void)ws_size;
  unsigned char* ws = (unsigned char*)d_ws;
  // zero h-ring and all sync flags every call (replay-safe).
  // Sb needs no memset: slot t is written before any read (t=0 s-GEMM skipped).
  hipMemsetAsync(ws + HR_OFF, 0, HR_BYTES, stream);
  hipMemsetAsync(ws + SYNC_OFF, 0, SYNC_BYTES, stream);
  lstmp_persistent<<<dim3(NWG), dim3(NTHR), 0, stream>>>(
      (const float*)d_in[0],
      (const float*)d_in[1], (const float*)d_in[2], (const float*)d_in[3],
      (const float*)d_in[4], (const float*)d_in[5], (const float*)d_in[6],
      (const float*)d_in[7], (const float*)d_in[8], (const float*)d_in[9],
      (float*)d_out, ws);
}

// Round 15
// 5287.083 us; speedup vs baseline: 1.5154x; 1.5154x over previous
//
#include <hip/hip_runtime.h>
#include <hip/hip_bf16.h>

typedef __attribute__((ext_vector_type(4))) float f32x4;
typedef __attribute__((ext_vector_type(8))) short s16x8;

#define DEVFN static __device__ __forceinline__

// ---- problem sizes ----
#define TT  160
#define BB  640
#define DD  40
#define HH  768
#define PP  256
#define G4H 3072

// ---- geometry ----
#define NWG   192
#define NTHR  512      // 8 waves -> 2 waves/SIMD (R13-proven)

#define KH  256
#define KX0 64         // layer0 x-K padded 40 -> 64

// LDS strides (elements), +8 pad keeps 16B alignment and breaks worst conflicts
#define STW1 328       // layer0: 320+8
#define STW2 520       // layer1/2: 512+8
#define STP  776       // proj: 768+8
#define LDS_ELEMS 66560  // 128*520 = 133,120 bytes

// ---- workspace layout ----
// Sb is a DEPTH-4 ring: one acquire-fence per 4 steps suffices (R12-proven).
#define XP_BYTES   (TT*BB*64*2)
#define HR_BYTES   (3*4*BB*PP*2)
#define SB_BYTES   (3*4*BB*HH*2)
#define XP_OFF     0
#define HR_OFF     (XP_OFF + XP_BYTES)
#define SB_OFF     (HR_OFF + HR_BYTES)
#define SYNC_OFF   (SB_OFF + SB_BYTES)
#define SYNC_BYTES 4096

DEVFN float sigm(float v)  { return __fdividef(1.f, 1.f + __expf(-v)); }
DEVFN float tanh_(float v) { return 2.f * __fdividef(1.f, 1.f + __expf(-2.f * v)) - 1.f; }
DEVFN f32x4 f4zero() { f32x4 v; v[0]=0.f; v[1]=0.f; v[2]=0.f; v[3]=0.f; return v; }

// write-through bf16 store: at coherence point once vmcnt retires (R8-proven).
DEVFN void gst_b16(__hip_bfloat16* p, __hip_bfloat16 v) {
  unsigned short u = __builtin_bit_cast(unsigned short, v);
  asm volatile("global_store_short %0, %1, off sc0 sc1" :: "v"(p), "v"(u));
}

// cache-bypassing 4B load/store (coherence-point access, fresh values)
DEVFN unsigned ld_cc(const unsigned* p) {
  unsigned v;
  asm volatile("global_load_dword %0, %1, off sc0 sc1\n\ts_waitcnt vmcnt(0)"
               : "=v"(v) : "v"(p) : "memory");
  return v;
}
DEVFN void st_cc(unsigned* p, unsigned v) {
  asm volatile("global_store_dword %0, %1, off sc0 sc1" :: "v"(p), "v"(v) : "memory");
}
DEVFN void ld3_cc(const unsigned* p0, const unsigned* p1, const unsigned* p2,
                  unsigned& a, unsigned& b, unsigned& c) {
  asm volatile("global_load_dword %0, %3, off sc0 sc1\n\t"
               "global_load_dword %1, %4, off sc0 sc1\n\t"
               "global_load_dword %2, %5, off sc0 sc1\n\t"
               "s_waitcnt vmcnt(0)"
               : "=&v"(a), "=&v"(b), "=&v"(c)
               : "v"(p0), "v"(p1), "v"(p2) : "memory");
}

DEVFN void fence_acq() { __builtin_amdgcn_fence(__ATOMIC_ACQUIRE, "agent"); }

// ---- sync word layout (unsigned, within 4096B):
//   [0..191]   init-barrier flags (one per block)
//   SFLAG(l,g) = 256 + (l*48+g)*4   gate-block "Sb(t) done" counters (value t+1)
//   PFLAG(l,p) = 832 + (l*16+p)*4   proj-block "h(t) done"  counters (value t+1)
#define SFLAG(s,l,g) ((s) + 256 + ((l)*48+(g))*4)
#define PFLAG(s,l,p) ((s) + 832 + ((l)*16+(p))*4)

// one-time full-grid barrier (packs done); decentralized: every block polls all 192.
DEVFN void init_barrier(unsigned* sync, int bid, int tid) {
  __syncthreads();                 // drains vmcnt: Xp pack stores at coherence point
  if (tid == 0) st_cc(sync + bid, 1u);
  if (tid < 64) {
    unsigned a, b, c;
    for (;;) {
      ld3_cc(sync + tid, sync + 64 + tid, sync + 128 + tid, a, b, c);
      if (__all((a >= 1u) & (b >= 1u) & (c >= 1u))) break;
    }
    fence_acq();
  }
  __syncthreads();
}

// wait until nf flags (16B stride) all >= thr. Busy spin. Acquire fence only
// when dofence (ring-amortized: one fence per ring period suffices).
DEVFN void wait_flags(const unsigned* base, int nf, int thr, int tid, bool dofence) {
  if (thr <= 0) return;
  if (tid < 64) {
    const unsigned* p = base + tid * 4;
    for (;;) {
      int v = (tid < nf) ? (int)ld_cc(p) : 0x7fffffff;
      if (__all(v >= thr)) break;
    }
    if (dofence) fence_acq();
  }
  __syncthreads();
}

// proj wait: OWN-HALF gate flags (24) >= thr1, plus (l<2) ring back-pressure
// on the same half's layer-(l+1) gate flags >= thr2 (slack 3, rarely binds).
DEVFN void wait_proj(const unsigned* sf_l, const unsigned* sf_lp1, int has2,
                     int thr1, int thr2, int tid, bool dofence) {
  if (tid < 64) {
    const unsigned* p1 = sf_l + tid * 4;
    const unsigned* p2 = sf_lp1 + tid * 4;
    for (;;) {
      int v1 = (tid < 24) ? (int)ld_cc(p1) : 0x7fffffff;
      int v2 = (has2 && tid < 24 && thr2 > 0) ? (int)ld_cc(p2) : 0x7fffffff;
      if (__all((v1 >= thr1) & (v2 >= thr2))) break;
    }
    if (dofence) fence_acq();
  }
  __syncthreads();
}

// announce: data stores drained (syncthreads => vmcnt(0)), then flag store.
DEVFN void set_flag(unsigned* p, unsigned v, int tid) {
  __syncthreads();
  if (tid == 0) st_cc(p, v);
}

__global__ __launch_bounds__(NTHR, 1)
void lstmp_persistent(const float* __restrict__ xin,
                      const float* __restrict__ W0, const float* __restrict__ b0, const float* __restrict__ Wp0,
                      const float* __restrict__ W1, const float* __restrict__ b1, const float* __restrict__ Wp1,
                      const float* __restrict__ W2, const float* __restrict__ b2, const float* __restrict__ Wp2,
                      float* __restrict__ outp, unsigned char* __restrict__ ws)
{
  __shared__ __align__(16) __hip_bfloat16 lds[LDS_ELEMS];

  const int bid  = blockIdx.x;
  const int tid  = threadIdx.x;
  const int lane = tid & 63;
  const int wave = tid >> 6;      // 0..7
  const int q    = lane >> 4;     // 0..3
  const int c16  = lane & 15;

  __hip_bfloat16* Xp = (__hip_bfloat16*)(ws + XP_OFF);  // [160][640][64] bf16, cols>=40 zero
  __hip_bfloat16* Hr = (__hip_bfloat16*)(ws + HR_OFF);  // [3][4 ring][640][256] bf16; slot (t+1)&3 holds h(t)
  __hip_bfloat16* Sb = (__hip_bfloat16*)(ws + SB_OFF);  // [3][4 ring][640][768] bf16; slot t&3 holds s(t)
  unsigned* sync     = (unsigned*)(ws + SYNC_OFF);

  // ---- XCD-aware role decode (performance heuristic only; correctness is
  // placement-independent -- all sync goes through the coherence point).
  const int xcd  = bid & 7;
  const int slot = bid >> 3;      // 0..23
  const bool isGate = (xcd < 6);
  int l = 0, bc = 0, hg = 0, mt = 0, nt = 0;
  if (isGate) { l = xcd >> 1; bc = xcd & 1; hg = slot; }
  else        { l = slot >> 3; int r = slot & 7; mt = (xcd - 6) * 2 + (r >> 2); nt = r & 3; }

  const int KX  = (l == 0) ? KX0 : 256;
  const int KT  = KX + KH;                  // 320 or 512
  const int STW = (l == 0) ? STW1 : STW2;

  const float* Wl  = (l == 0) ? W0  : ((l == 1) ? W1  : W2);
  const float* bl  = (l == 0) ? b0  : ((l == 1) ? b1  : b2);
  const float* Wpl = (l == 0) ? Wp0 : ((l == 1) ? Wp1 : Wp2);

  // ---------- pre-phase: pack x -> Xp (all blocks share the work) ----------
  for (int e = bid * NTHR + tid; e < TT * BB * 64; e += NWG * NTHR) {
    int k  = e & 63;
    int tb = e >> 6;
    float v = (k < DD) ? xin[(size_t)tb * DD + k] : 0.f;
    gst_b16(&Xp[e], __float2bfloat16(v));
  }

  // ---------- pre-phase: pack weights (transposed) into this block's LDS ----------
  if (isGate) {
    for (int idx = tid; idx < 128 * KT; idx += NTHR) {
      int kk = idx >> 7;
      int nn = idx & 127;
      int col = (nn >> 5) * HH + hg * 32 + (nn & 31);
      float v;
      if (l == 0) {
        v = (kk < DD) ? Wl[(size_t)kk * G4H + col]
                      : ((kk < KX0) ? 0.f : Wl[(size_t)(kk - 24) * G4H + col]);
      } else {
        v = Wl[(size_t)kk * G4H + col];
      }
      lds[nn * STW + kk] = __float2bfloat16(v);
    }
  } else {
    for (int idx = tid; idx < 64 * HH; idx += NTHR) {
      int kk = idx >> 6;
      int nn = idx & 63;
      lds[nn * STP + kk] = __float2bfloat16(Wpl[(size_t)kk * PP + nt * 64 + nn]);
    }
  }

  init_barrier(sync, bid, tid);     // packs done (Xp + LDS weights)

  if (isGate) {
    // ----- GATE PATH: 8 waves = 4 row-groups (80 rows) x 2 col-groups -----
    const int gid = bc * 24 + hg;
    unsigned* myflag = SFLAG(sync, l, gid);
    const unsigned* pf_own = PFLAG(sync, l, bc * 8);
    const unsigned* pf_prv = (l > 0) ? PFLAG(sync, l - 1, bc * 8) : PFLAG(sync, l, bc * 8);

    const int wmg = wave >> 1, wng = wave & 1;
    const int m0g = bc * 320 + wmg * 80;       // this wave's 80-row base
    const int hcl = wng * 16 + c16;            // 0..31 within WG's 32 h-cols
    float biasv[4];
#pragma unroll
    for (int g = 0; g < 4; ++g) biasv[g] = bl[g * HH + hg * 32 + hcl];

    f32x4 acc[5][4];     // 80 VGPR: wave covers 80 rows x 16 cols x 4 gates
    float cst[5][4];
#pragma unroll
    for (int mi = 0; mi < 5; ++mi)
#pragma unroll
      for (int g = 0; g < 4; ++g) { acc[mi][g] = f4zero(); cst[mi][g] = 0.f; }

    // K=256 GEMM with 4-deep slice prefetch ring (proj's R10 PSLICE mechanism
    // applied to the CRITICAL gate chain): 20 A-loads in flight, each slice's
    // loads covered by ~3 slices of MFMA before consumption. A's K-offset is
    // ks only (A starts at k=0); kbase applies to the LDS B-tile rows only.
    auto gate_g256 = [&](const __hip_bfloat16* A, int lda, int kbase) {
      const __hip_bfloat16* ab[5];
#pragma unroll
      for (int mi = 0; mi < 5; ++mi)
        ab[mi] = A + (size_t)(m0g + mi * 16 + c16) * lda + 8 * q;
      s16x8 r0[5], r1[5], r2[5], r3[5];
#pragma unroll
      for (int mi = 0; mi < 5; ++mi) {
        r0[mi] = *(const s16x8*)(ab[mi] + 0);
        r1[mi] = *(const s16x8*)(ab[mi] + 32);
        r2[mi] = *(const s16x8*)(ab[mi] + 64);
        r3[mi] = *(const s16x8*)(ab[mi] + 96);
      }
#define GSLICE(RB, S)                                                          \
      {                                                                        \
        s16x8 bv[4];                                                           \
        _Pragma("unroll")                                                      \
        for (int g = 0; g < 4; ++g)                                            \
          bv[g] = *(const s16x8*)(lds + (g * 32 + hcl) * STW + kbase + (S) * 32 + 8 * q); \
        _Pragma("unroll")                                                      \
        for (int mi = 0; mi < 5; ++mi)                                         \
          _Pragma("unroll")                                                    \
          for (int g = 0; g < 4; ++g)                                          \
            acc[mi][g] = __builtin_amdgcn_mfma_f32_16x16x32_bf16(RB[mi], bv[g], acc[mi][g], 0, 0, 0); \
        if ((S) + 4 < 8) {                                                     \
          _Pragma("unroll")                                                    \
          for (int mi = 0; mi < 5; ++mi)                                       \
            RB[mi] = *(const s16x8*)(ab[mi] + ((S) + 4) * 32);                 \
        }                                                                      \
      }
      GSLICE(r0, 0) GSLICE(r1, 1) GSLICE(r2, 2) GSLICE(r3, 3)
      GSLICE(r0, 4) GSLICE(r1, 5) GSLICE(r2, 6) GSLICE(r3, 7)
#undef GSLICE
    };

    // K=64 GEMM (layer-0 x-part): both slices prefetched up front.
    auto gate_g64 = [&](const __hip_bfloat16* A, int lda) {
      s16x8 a0[5], a1[5];
#pragma unroll
      for (int mi = 0; mi < 5; ++mi) {
        const __hip_bfloat16* ap = A + (size_t)(m0g + mi * 16 + c16) * lda + 8 * q;
        a0[mi] = *(const s16x8*)(ap);
        a1[mi] = *(const s16x8*)(ap + 32);
      }
      s16x8 bv[4];
#pragma unroll
      for (int g = 0; g < 4; ++g)
        bv[g] = *(const s16x8*)(lds + (g * 32 + hcl) * STW + 8 * q);
#pragma unroll
      for (int mi = 0; mi < 5; ++mi)
#pragma unroll
        for (int g = 0; g < 4; ++g)
          acc[mi][g] = __builtin_amdgcn_mfma_f32_16x16x32_bf16(a0[mi], bv[g], acc[mi][g], 0, 0, 0);
#pragma unroll
      for (int g = 0; g < 4; ++g)
        bv[g] = *(const s16x8*)(lds + (g * 32 + hcl) * STW + 32 + 8 * q);
#pragma unroll
      for (int mi = 0; mi < 5; ++mi)
#pragma unroll
        for (int g = 0; g < 4; ++g)
          acc[mi][g] = __builtin_amdgcn_mfma_f32_16x16x32_bf16(a1[mi], bv[g], acc[mi][g], 0, 0, 0);
    };

    auto gate_update = [&](int t) {
      __hip_bfloat16* S = Sb + ((size_t)l * 4 + ((unsigned)t & 3)) * BB * HH;
#pragma unroll
      for (int mi = 0; mi < 5; ++mi) {
#pragma unroll
        for (int r = 0; r < 4; ++r) {
          float iv = acc[mi][0][r] + biasv[0];
          float jv = acc[mi][1][r] + biasv[1];
          float fv = acc[mi][2][r] + biasv[2];
          float ov = acc[mi][3][r] + biasv[3];
          float c  = sigm(fv + 1.f) * cst[mi][r] + sigm(iv) * tanh_(jv);
          cst[mi][r] = c;
          float sv = sigm(ov) * tanh_(c);
          gst_b16(&S[(size_t)(m0g + mi * 16 + q * 4 + r) * HH + hg * 32 + hcl],
                  __float2bfloat16(sv));
        }
#pragma unroll
        for (int g = 0; g < 4; ++g) acc[mi][g] = f4zero();
      }
    };

    // zx(0): layer0 from Xp; l>0 from h_{l-1}(0) once the own-half proj flags show t'=0.
    if (l == 0) gate_g64(Xp, 64);
    else {
      wait_flags(pf_prv, 8, 1, tid, true);
      gate_g256(Hr + ((size_t)(l - 1) * 4 + 1) * BB * PP, PP, 0);
    }

    for (int t = 0; t < TT; ++t) {
      // h_l(t-1) ready when own-half proj flags >= t. Fence once per ring
      // period (4): covers this wait's Hr slot AND the shadow's Hr_{l-1} slot.
      wait_flags(pf_own, 8, t, tid, (t & 3) == 0);
      gate_g256(Hr + ((size_t)l * 4 + ((unsigned)t & 3)) * BB * PP, PP, KX);
      gate_update(t);
      set_flag(myflag, (unsigned)(t + 1), tid);
      // x-shadow zx(t+1): runs in proj's shadow; NO fence (covered above)
      if (t + 1 < TT) {
        if (l == 0) gate_g64(Xp + (size_t)(t + 1) * BB * 64, 64);
        else {
          wait_flags(pf_prv, 8, t + 2, tid, false);
          gate_g256(Hr + ((size_t)(l - 1) * 4 + ((unsigned)(t + 2) & 3)) * BB * PP, PP, 0);
        }
      }
    }
  } else {
    // ----- PROJ PATH: waves 0-3 do the (off-critical) work; waves 4-7 idle
    // through the syncs. Lean registers, 4-deep prefetch ring. -----
    const int pid = mt * 4 + nt;
    const int bch = mt >> 1;                 // this proj block's batch half
    unsigned* myflag = PFLAG(sync, l, pid);
    const unsigned* sf_own = SFLAG(sync, l, bch * 24);
    const unsigned* sf_nxt = (l < 2) ? SFLAG(sync, l + 1, bch * 24) : SFLAG(sync, l, bch * 24);
    const int m0p = mt * 160 + ((wave & 3) >> 1) * 80;
    const int np0 = (wave & 1) * 32;

    for (int t = 0; t < TT; ++t) {
      // Sb_l(t) ready (own-half 24 gate flags >= t+1); back-pressure slack 3.
      wait_proj(sf_own, sf_nxt, l < 2 ? 1 : 0, t + 1, t - 3, tid, (t & 3) == 0);

      if (wave < 4) {
        const __hip_bfloat16* A = Sb + ((size_t)l * 4 + ((unsigned)t & 3)) * BB * HH;
        const __hip_bfloat16* ab[5];
#pragma unroll
        for (int mi = 0; mi < 5; ++mi)
          ab[mi] = A + (size_t)(m0p + mi * 16 + c16) * HH + 8 * q;

        f32x4 pa[5][2];
#pragma unroll
        for (int mi = 0; mi < 5; ++mi) { pa[mi][0] = f4zero(); pa[mi][1] = f4zero(); }

        s16x8 r0[5], r1[5], r2[5], r3[5];   // 4-deep static prefetch ring
#pragma unroll
        for (int mi = 0; mi < 5; ++mi) {
          r0[mi] = *(const s16x8*)(ab[mi] + 0);
          r1[mi] = *(const s16x8*)(ab[mi] + 32);
          r2[mi] = *(const s16x8*)(ab[mi] + 64);
          r3[mi] = *(const s16x8*)(ab[mi] + 96);
        }

#define PSLICE(RB, S)                                                          \
        {                                                                      \
          s16x8 bv0 = *(const s16x8*)(lds + (np0 + c16) * STP + (S) * 32 + 8 * q);      \
          s16x8 bv1 = *(const s16x8*)(lds + (np0 + 16 + c16) * STP + (S) * 32 + 8 * q); \
          _Pragma("unroll")                                                    \
          for (int mi = 0; mi < 5; ++mi) {                                     \
            pa[mi][0] = __builtin_amdgcn_mfma_f32_16x16x32_bf16(RB[mi], bv0, pa[mi][0], 0, 0, 0); \
            pa[mi][1] = __builtin_amdgcn_mfma_f32_16x16x32_bf16(RB[mi], bv1, pa[mi][1], 0, 0, 0); \
          }                                                                    \
          if ((S) + 4 < 24) {                                                  \
            _Pragma("unroll")                                                  \
            for (int mi = 0; mi < 5; ++mi)                                     \
              RB[mi] = *(const s16x8*)(ab[mi] + ((S) + 4) * 32);               \
          }                                                                    \
        }

        PSLICE(r0, 0)  PSLICE(r1, 1)  PSLICE(r2, 2)  PSLICE(r3, 3)
        PSLICE(r0, 4)  PSLICE(r1, 5)  PSLICE(r2, 6)  PSLICE(r3, 7)
        PSLICE(r0, 8)  PSLICE(r1, 9)  PSLICE(r2, 10) PSLICE(r3, 11)
        PSLICE(r0, 12) PSLICE(r1, 13) PSLICE(r2, 14) PSLICE(r3, 15)
        PSLICE(r0, 16) PSLICE(r1, 17) PSLICE(r2, 18) PSLICE(r3, 19)
        PSLICE(r0, 20) PSLICE(r1, 21) PSLICE(r2, 22) PSLICE(r3, 23)
#undef PSLICE

        __hip_bfloat16* Hd = Hr + ((size_t)l * 4 + ((unsigned)(t + 1) & 3)) * BB * PP;
#pragma unroll
        for (int mi = 0; mi < 5; ++mi)
#pragma unroll
          for (int ni = 0; ni < 2; ++ni)
#pragma unroll
            for (int r = 0; r < 4; ++r)
              gst_b16(&Hd[(size_t)(m0p + mi * 16 + q * 4 + r) * PP + nt * 64 + np0 + ni * 16 + c16],
                      __float2bfloat16(pa[mi][ni][r]));
      }

      set_flag(myflag, (unsigned)(t + 1), tid);
    }
  }

  // ---------- epilogue: L2-normalize h_2(159) (ring slot (159+1)&3 = 0) ----------
  wait_flags(PFLAG(sync, 2, 0), 16, TT, tid, true);
  const __hip_bfloat16* hf = Hr + (size_t)(2 * 4 + 0) * BB * PP;
  float* red = reinterpret_cast<float*>(lds);   // weights dead now, reuse LDS
  const int half = tid >> 8;                    // 0,1: two rows per iteration
  const int col  = tid & 255;
  for (int row0 = bid * 2; row0 < BB; row0 += NWG * 2) {
    const int row = row0 + half;
    float v = __bfloat162float(hf[(size_t)row * PP + col]);
    float ssq = v * v;
#pragma unroll
    for (int off = 32; off > 0; off >>= 1) ssq += __shfl_down(ssq, off, 64);
    if (lane == 0) red[wave] = ssq;
    __syncthreads();
    float tot = red[half * 4 + 0] + red[half * 4 + 1] + red[half * 4 + 2] + red[half * 4 + 3];
    outp[(size_t)row * PP + col] = v * __fdividef(1.f, sqrtf(tot) + 1e-6f);
    __syncthreads();
  }
}

extern "C" void kernel_launch(void* const* d_in, const int* in_sizes, int n_in,
                              void* d_out, int out_size, void* d_ws, size_t ws_size,
                              hipStream_t stream) {
  (void)in_sizes; (void)n_in; (void)out_size; (void)ws_size;
  unsigned char* ws = (unsigned char*)d_ws;
  // zero h-ring (h_{-1} = 0) and all sync flags every call (replay-safe).
  // Sb needs no memset: every slot is written before its first read.
  hipMemsetAsync(ws + HR_OFF, 0, HR_BYTES, stream);
  hipMemsetAsync(ws + SYNC_OFF, 0, SYNC_BYTES, stream);
  lstmp_persistent<<<dim3(NWG), dim3(NTHR), 0, stream>>>(
      (const float*)d_in[0],
      (const float*)d_in[1], (const float*)d_in[2], (const float*)d_in[3],
      (const float*)d_in[4], (const float*)d_in[5], (const float*)d_in[6],
      (const float*)d_in[7], (const float*)d_in[8], (const float*)d_in[9],
      (float*)d_out, ws);
}